// Round 15
// baseline (72.026 us; speedup 1.0000x reference)
//
#include <hip/hip_runtime.h>
#include <math.h>

#define BB 8
#define SS 4096
#define DD 1024
#define HH 16

typedef __attribute__((ext_vector_type(4))) float f32x4;
typedef __fp16 fp16x2 __attribute__((ext_vector_type(2)));
typedef _Float16 half8v __attribute__((ext_vector_type(8)));

// ws layout (no aliasing):
//   plog    [BB][SS][HH] fp32 = 2 MB   @ 0      (scaled+masked logits)
//   partial [32][BB][HH][DD]  = 16 MB  @ 6 MB
//   wh16/wl16 fp16 frag streams 32+32 KB @ 22 MB
//   bred    [BB][256][HH] float2 = 32 KB @ 23 MB (per-16-row-tile (m,Z))

__device__ __forceinline__ void sm_merge(float& m, float& z, float om, float oz) {
  float nm = fmaxf(m, om);
  if (nm > -INFINITY)
    z = z * __expf(m - nm) + oz * __expf(om - nm);
  m = nm;
}

// K0: W fp16 hi/lo frag streams. Element e of lane l at K-step t <-> k =
// t*32 + (l>>4)*8 + e, col h = l&15. Layout [t][lane][e], t = 0..31.
__global__ __launch_bounds__(256) void k_prepw(
    const float* __restrict__ W, ushort* __restrict__ wh16, ushort* __restrict__ wl16) {
  int i = blockIdx.x * 256 + threadIdx.x;  // 16384
  int t = i >> 9;
  int l = (i >> 3) & 63;
  int e = i & 7;
  int d = t * 32 + (l >> 4) * 8 + e;
  int h = l & 15;
  float w = W[d * HH + h];
  _Float16 wh = (_Float16)w;               // RNE
  _Float16 wl = (_Float16)(w - (float)wh); // residual
  union { _Float16 f; ushort u; } ch, cl;
  ch.f = wh; cl.f = wl;
  wh16[i] = ch.u;
  wl16[i] = cl.u;
}

// K1 v9: ROW-STREAMED tile staging + K-split across waves.
// Each wave reads 4 ADJACENT FULL rows (contiguous 16 KB span, k_pool-style
// row-major streaming) into a shared 64 KB [16 rows][1024] tile; then wave wv
// MFMAs K-quarter [wv*256, wv*256+256) of all 16 rows; cross-wave fp32
// reduce; epilogue emits masked logits + per-tile softmax (m,Z).
// grid 2048 (= 8 b x 256 tiles of 16 rows), block 256 (4 waves), 2 blocks/CU.
__global__ __launch_bounds__(256, 2) void k_logits(
    const float* __restrict__ x, const ushort* __restrict__ wh16,
    const ushort* __restrict__ wl16, const int* __restrict__ mask,
    float* __restrict__ plog, float2* __restrict__ bred) {
  __shared__ float4 xt[16][256];    // 64 KB x-tile, slot-XOR-swizzled
  __shared__ float red[4][16][16];  // 4 KB cross-wave K-reduce
  __shared__ float lt[16][17];      // logit tile (+1 pad)

  const int tid = threadIdx.x;
  const int lane = tid & 63;
  const int wv = tid >> 6;
  const int b = blockIdx.x >> 8;
  const int tile = blockIdx.x & 255;
  const int r15 = lane & 15;   // A row / D col (h)
  const int kg = lane >> 4;    // k-group

  const float* xbase = x + ((size_t)b * SS + tile * 16) * DD;

  // ---- stage: wave wv streams rows wv*4..wv*4+3 (contiguous 16 KB) ----
  float4 stv[16];
#pragma unroll
  for (int rr = 0; rr < 4; ++rr) {
#pragma unroll
    for (int q = 0; q < 4; ++q)
      stv[rr * 4 + q] = *reinterpret_cast<const float4*>(
          xbase + (size_t)(wv * 4 + rr) * DD + q * 256 + lane * 4);
  }
#pragma unroll
  for (int rr = 0; rr < 4; ++rr) {
    int row = wv * 4 + rr;
#pragma unroll
    for (int q = 0; q < 4; ++q) {
      int slot = q * 64 + lane;
      xt[row][slot ^ (row & 7)] = stv[rr * 4 + q];
    }
  }
  __syncthreads();

  // ---- compute: wave wv owns K in [wv*256, wv*256+256) ----
  // Frag map: k = t_glob*32 + kg*8 + e with t_glob = wv*8 + t  (matches K0).
  const half8v* bhp = reinterpret_cast<const half8v*>(wh16) + lane;
  const half8v* blp = reinterpret_cast<const half8v*>(wl16) + lane;

  f32x4 acch = {0.f, 0.f, 0.f, 0.f};
  f32x4 accl = {0.f, 0.f, 0.f, 0.f};
#pragma unroll
  for (int t = 0; t < 8; ++t) {
    const int tg = wv * 8 + t;
    half8v bh = bhp[tg * 64];
    half8v bl = blp[tg * 64];
    const int slot = wv * 64 + t * 8 + kg * 2;
    float4 va = xt[r15][slot ^ (r15 & 7)];
    float4 vb = xt[r15][(slot + 1) ^ (r15 & 7)];
    union { fp16x2 h2[4]; half8v h8; } ax;
    ax.h2[0] = __builtin_amdgcn_cvt_pkrtz(va.x, va.y);
    ax.h2[1] = __builtin_amdgcn_cvt_pkrtz(va.z, va.w);
    ax.h2[2] = __builtin_amdgcn_cvt_pkrtz(vb.x, vb.y);
    ax.h2[3] = __builtin_amdgcn_cvt_pkrtz(vb.z, vb.w);
    acch = __builtin_amdgcn_mfma_f32_16x16x32_f16(ax.h8, bh, acch, 0, 0, 0);
    accl = __builtin_amdgcn_mfma_f32_16x16x32_f16(ax.h8, bl, accl, 0, 0, 0);
  }

  // ---- cross-wave K-reduce (D layout: col=r15(h), row=kg*4+q; m89) ----
#pragma unroll
  for (int q = 0; q < 4; ++q)
    red[wv][kg * 4 + q][r15] = acch[q] + accl[q];
  __syncthreads();

  {
    const int s = tid >> 4, h = tid & 15;  // 256 threads cover 16x16
    float v = (red[0][s][h] + red[1][s][h] + red[2][s][h] + red[3][s][h]) * 0.125f;
    int msk = mask[b * SS + tile * 16 + s];
    float lv = msk ? v : -INFINITY;
    plog[((size_t)b * SS + tile * 16 + s) * HH + h] = lv;  // coalesced 1 KB
    lt[s][h] = lv;
  }
  __syncthreads();

  if (tid < 16) {  // per-h serial 16-row scan (transparent)
    float m = -INFINITY;
    for (int s = 0; s < 16; ++s) m = fmaxf(m, lt[s][tid]);
    float Z = 0.f;
    if (m > -INFINITY) {
      for (int s = 0; s < 16; ++s) {
        float v = lt[s][tid];
        Z += (v > -INFINITY) ? __expf(v - m) : 0.f;
      }
    }
    bred[((size_t)b * 256 + tile) * HH + tid] = make_float2(m, Z);
  }
}

// K3: pooling with inline softmax finalize (R10 config: grid 512 = 8b x 32sc x 2dh).
__global__ __launch_bounds__(256) void k_pool(
    const float* __restrict__ x, const float* __restrict__ plog,
    const float2* __restrict__ bred, const int* __restrict__ mask,
    float* __restrict__ partial) {
  __shared__ float wl[128][16];
  __shared__ float2 red2[16][16];
  __shared__ float fm[16], fz[16];
  const int tid = threadIdx.x;
  const int dh = blockIdx.x & 1;
  const int sc = (blockIdx.x >> 1) & 31;
  const int b = blockIdx.x >> 6;
  const int s0 = sc * 128;

  // two-level merge of 256 tile-partials (parallel level 1)
  {
    const int h = tid & 15, cg = tid >> 4;  // 16 chunk-groups
    float m = -INFINITY, z = 0.f;
#pragma unroll 4
    for (int i = 0; i < 16; ++i) {
      float2 p = bred[((size_t)b * 256 + cg * 16 + i) * HH + h];
      sm_merge(m, z, p.x, p.y);
    }
    red2[cg][h] = make_float2(m, z);
  }
  __syncthreads();
  if (tid < 16) {
    float m = -INFINITY, z = 0.f;
#pragma unroll
    for (int g = 0; g < 16; ++g) {
      float2 p = red2[g][tid];
      sm_merge(m, z, p.x, p.y);
    }
    fm[tid] = m;
    fz[tid] = (z > 0.f) ? 1.0f / z : 0.f;
  }
  __syncthreads();

  const float4* p0 = reinterpret_cast<const float4*>(plog + ((size_t)b * SS + s0) * HH);
  const int* mb = mask + b * SS + s0;
#pragma unroll
  for (int k = 0; k < 2; ++k) {
    int f = k * 256 + tid;  // float4 over [128][16]
    float4 va = p0[f];
    int msk = mb[f >> 2];
    int hb = (f & 3) * 4;
    float4 w;
    w.x = msk ? __expf(va.x - fm[hb + 0]) * fz[hb + 0] : 0.f;
    w.y = msk ? __expf(va.y - fm[hb + 1]) * fz[hb + 1] : 0.f;
    w.z = msk ? __expf(va.z - fm[hb + 2]) * fz[hb + 2] : 0.f;
    w.w = msk ? __expf(va.w - fm[hb + 3]) * fz[hb + 3] : 0.f;
    *reinterpret_cast<float4*>(&wl[0][0] + f * 4) = w;
  }
  __syncthreads();

  float2 acc[HH];
#pragma unroll
  for (int h = 0; h < HH; ++h) acc[h] = make_float2(0.f, 0.f);

  const float* xb = x + ((size_t)b * SS + s0) * DD + dh * 512 + tid * 2;
  for (int s = 0; s < 128; ++s) {
    float2 xv = *reinterpret_cast<const float2*>(xb + (size_t)s * DD);
    const float4* wrow = reinterpret_cast<const float4*>(wl[s]);
    float4 wa = wrow[0], wb_ = wrow[1], wc = wrow[2], wd = wrow[3];
    float wvv[16] = {wa.x, wa.y, wa.z, wa.w, wb_.x, wb_.y, wb_.z, wb_.w,
                     wc.x, wc.y, wc.z, wc.w, wd.x, wd.y, wd.z, wd.w};
#pragma unroll
    for (int h = 0; h < HH; ++h) {
      float w = wvv[h];
      acc[h].x += w * xv.x;
      acc[h].y += w * xv.y;
    }
  }

  float* pb = partial + ((size_t)sc * BB + b) * (HH * DD) + dh * 512 + tid * 2;
#pragma unroll
  for (int h = 0; h < HH; ++h)
    *reinterpret_cast<float2*>(pb + (size_t)h * DD) = acc[h];
}

// K4: reduce 32 s-chunk partials. grid 512, block 256.
__global__ __launch_bounds__(256) void k_reduce(
    const float* __restrict__ partial, float* __restrict__ out) {
  const int idx = blockIdx.x * 256 + threadIdx.x;
  float s = 0.f;
#pragma unroll
  for (int c = 0; c < 32; ++c) s += partial[(size_t)c * (BB * HH * DD) + idx];
  out[idx] = s;
}

extern "C" void kernel_launch(void* const* d_in, const int* in_sizes, int n_in,
                              void* d_out, int out_size, void* d_ws, size_t ws_size,
                              hipStream_t stream) {
  const float* x = (const float*)d_in[0];     // [8][4096][1024] fp32
  const float* W = (const float*)d_in[1];     // [1024][16] fp32
  const int* mask = (const int*)d_in[2];      // [8][4096] int32
  float* out = (float*)d_out;                 // [8][16384] fp32

  char* ws = (char*)d_ws;
  float* plog    = (float*)ws;                                   // 2 MB
  float* partial = (float*)(ws + (size_t)6 * 1024 * 1024);       // 16 MB
  ushort* wh16   = (ushort*)(ws + (size_t)22 * 1024 * 1024);     // 32 KB
  ushort* wl16   = (ushort*)(ws + (size_t)22 * 1024 * 1024 + 32 * 1024);
  float2* bred   = (float2*)(ws + (size_t)23 * 1024 * 1024);     // 32 KB

  k_prepw<<<64, 256, 0, stream>>>(W, wh16, wl16);
  k_logits<<<2048, 256, 0, stream>>>(x, wh16, wl16, mask, plog, bred);
  k_pool<<<512, 256, 0, stream>>>(x, plog, bred, mask, partial);
  k_reduce<<<512, 256, 0, stream>>>(partial, out);
}